// Round 1
// baseline (131.475 us; speedup 1.0000x reference)
//
#include <hip/hip_runtime.h>
#include <hip/hip_bf16.h>

typedef __attribute__((ext_vector_type(8))) short short8;
typedef __attribute__((ext_vector_type(4))) float f32x4;

#define N1 768
#define N2 768
#define LL 128
#define NS 30

// float -> bf16 bits, round-to-nearest-even (data has no NaN)
__device__ __forceinline__ unsigned short f2b(float f) {
  unsigned int u = __float_as_uint(f);
  unsigned int r = (u + 0x7fffu + ((u >> 16) & 1u)) >> 16;
  return (unsigned short)r;
}

__device__ __forceinline__ float b2f(unsigned short b) {
  return __uint_as_float(((unsigned int)b) << 16);
}

// ---------------------------------------------------------------------------
// prep: S = A@A^T (30x30 f32), w = sigmoid(W) from w_vec (128x128, f32 + bf16)
// ---------------------------------------------------------------------------
__global__ void prep_kernel(const float* __restrict__ A, const float* __restrict__ w_vec,
                            float* __restrict__ S, float* __restrict__ wf,
                            unsigned short* __restrict__ wb) {
  int t = threadIdx.x;
  for (int idx = t; idx < NS * NS; idx += 256) {
    int s = idx / NS, u = idx - s * NS;
    float acc = 0.f;
#pragma unroll
    for (int k = 0; k < 16; ++k) acc += A[s * 16 + k] * A[u * 16 + k];
    S[idx] = acc;
  }
  for (int idx = t; idx < LL * LL; idx += 256) {
    int l = idx >> 7, m = idx & (LL - 1);
    float sig;
    if (l == m) {
      sig = 0.5f;  // sigmoid(0), diagonal of W stays 0
    } else {
      int hi = l > m ? l : m, lo = l > m ? m : l;
      float val = w_vec[hi * (hi - 1) / 2 + lo];  // tril_indices(L,-1) row-major
      sig = 1.f / (1.f + expf(-val));
    }
    wf[idx] = sig;
    wb[idx] = f2b(sig);
  }
}

// ---------------------------------------------------------------------------
// norm: inv_out[row] = scale / sqrt( d^T w d ),  d_l = S[x_l, x_l]
// one block (128 threads) per row
// ---------------------------------------------------------------------------
__global__ void norm_kernel(const int* __restrict__ X, const float* __restrict__ S,
                            const float* __restrict__ wf, float* __restrict__ inv_out,
                            const float* __restrict__ a_ptr, int use_a2) {
  __shared__ __align__(16) float d[LL];
  __shared__ float wsum[2];
  int row = blockIdx.x;
  int t = threadIdx.x;
  int x = X[row * LL + t];
  float dv = S[x * NS + x];
  d[t] = dv;
  __syncthreads();
  const float4* w4 = reinterpret_cast<const float4*>(wf + t * LL);
  const float4* d4 = reinterpret_cast<const float4*>(d);
  float s = 0.f;
#pragma unroll
  for (int m = 0; m < LL / 4; ++m) {
    float4 wv = w4[m];
    float4 dd = d4[m];
    s += wv.x * dd.x + wv.y * dd.y + wv.z * dd.z + wv.w * dd.w;
  }
  s *= dv;
#pragma unroll
  for (int off = 1; off < 64; off <<= 1) s += __shfl_xor(s, off);
  if ((t & 63) == 0) wsum[t >> 6] = s;
  __syncthreads();
  if (t == 0) {
    float k = wsum[0] + wsum[1];
    float scale = use_a2 ? a_ptr[0] * a_ptr[0] : 1.f;
    inv_out[row] = scale / sqrtf(k);
  }
}

// ---------------------------------------------------------------------------
// main: one block = 16x16 output tile (256 pairs). 4 waves.
//   V[p][l] = S[X1[i0+p/16, l], X2[j0+p%16, l]]  (bf16, LDS, XOR-swizzled)
//   E = V @ W via mfma_f32_16x16x32_bf16, K_p = sum_l E[p,l]*V[p,l]
// ---------------------------------------------------------------------------
__global__ __launch_bounds__(256) void main_kernel(
    const int* __restrict__ X1, const int* __restrict__ X2,
    const float* __restrict__ Sg, const unsigned short* __restrict__ wbg,
    const float* __restrict__ inv1, const float* __restrict__ inv2,
    float* __restrict__ out) {
  __shared__ __align__(16) float sS[NS * NS];
  __shared__ __align__(16) unsigned short sW[LL * LL];      // 32 KB, swizzled
  __shared__ __align__(16) unsigned short sV[256 * LL];     // 64 KB, swizzled
  __shared__ __align__(16) unsigned char x1T[LL][16];       // [l][ii]
  __shared__ __align__(16) unsigned char x2T[LL][16];       // [l][jj]

  const int t = threadIdx.x;
  const int i0 = blockIdx.y * 16, j0 = blockIdx.x * 16;
  char* sWb = reinterpret_cast<char*>(sW);
  char* sVb = reinterpret_cast<char*>(sV);

  // ---- stage S (900 f32 = 225 float4) ----
  if (t < 225)
    reinterpret_cast<float4*>(sS)[t] = reinterpret_cast<const float4*>(Sg)[t];

  // ---- stage W bf16 into swizzled LDS: 2048 x 16B chunks ----
#pragma unroll
  for (int c = 0; c < 8; ++c) {
    int ch = c * 256 + t;          // 0..2047
    int r = ch >> 4;               // row 0..127 (16 chunks per 256B row)
    int col8 = ch & 15;            // 16B chunk index in row
    uint4 v = reinterpret_cast<const uint4*>(wbg)[ch];
    *reinterpret_cast<uint4*>(sWb + r * 256 + ((col8 * 16) ^ ((r & 7) << 4))) = v;
  }

  // ---- stage index tiles, transposed to [l][row] bytes ----
  {
    int row = t >> 4, seg = t & 15;
    const int4* p1 = reinterpret_cast<const int4*>(X1 + (i0 + row) * LL + seg * 8);
    int4 a0 = p1[0], a1 = p1[1];
    x1T[seg * 8 + 0][row] = (unsigned char)a0.x;
    x1T[seg * 8 + 1][row] = (unsigned char)a0.y;
    x1T[seg * 8 + 2][row] = (unsigned char)a0.z;
    x1T[seg * 8 + 3][row] = (unsigned char)a0.w;
    x1T[seg * 8 + 4][row] = (unsigned char)a1.x;
    x1T[seg * 8 + 5][row] = (unsigned char)a1.y;
    x1T[seg * 8 + 6][row] = (unsigned char)a1.z;
    x1T[seg * 8 + 7][row] = (unsigned char)a1.w;
    const int4* p2 = reinterpret_cast<const int4*>(X2 + (j0 + row) * LL + seg * 8);
    int4 b0 = p2[0], b1 = p2[1];
    x2T[seg * 8 + 0][row] = (unsigned char)b0.x;
    x2T[seg * 8 + 1][row] = (unsigned char)b0.y;
    x2T[seg * 8 + 2][row] = (unsigned char)b0.z;
    x2T[seg * 8 + 3][row] = (unsigned char)b0.w;
    x2T[seg * 8 + 4][row] = (unsigned char)b1.x;
    x2T[seg * 8 + 5][row] = (unsigned char)b1.y;
    x2T[seg * 8 + 6][row] = (unsigned char)b1.z;
    x2T[seg * 8 + 7][row] = (unsigned char)b1.w;
  }
  __syncthreads();

  // ---- gather-build V: thread t owns column l = t&127, rows ii in one half ----
  {
    int l = t & 127, half = t >> 7;
    uint4 xw = *reinterpret_cast<const uint4*>(&x2T[l][0]);
    unsigned int xarr[4] = {xw.x, xw.y, xw.z, xw.w};
    int colbyte = 2 * l;
#pragma unroll
    for (int q = 0; q < 8; ++q) {
      int ii = half * 8 + q;
      const float* Srow = sS + (int)x1T[l][ii] * NS;
#pragma unroll
      for (int jj = 0; jj < 16; ++jj) {
        int x2v = (int)((xarr[jj >> 2] >> ((jj & 3) * 8)) & 0xffu);
        unsigned short b = f2b(Srow[x2v]);
        int p = ii * 16 + jj;  // (p&7) == (jj&7)
        *reinterpret_cast<unsigned short*>(sVb + p * 256 + (colbyte ^ ((p & 7) << 4))) = b;
      }
    }
  }
  __syncthreads();

  // ---- MFMA: E = V @ W, per wave 64 rows x 128 cols ----
  const int lane = t & 63, wave = t >> 6;
  f32x4 acc[4][8] = {};
#pragma unroll
  for (int kk = 0; kk < 4; ++kk) {
    int kb = kk * 64 + ((lane >> 4) << 4);  // byte offset of this lane's 16B k-chunk
    short8 af[4];
    short8 bf[8];
#pragma unroll
    for (int mt = 0; mt < 4; ++mt) {
      int p = wave * 64 + mt * 16 + (lane & 15);
      af[mt] = *reinterpret_cast<const short8*>(sVb + p * 256 + (kb ^ ((p & 7) << 4)));
    }
#pragma unroll
    for (int nt = 0; nt < 8; ++nt) {
      int n = nt * 16 + (lane & 15);
      // B[k][n] = w[k][n] = w[n][k] (symmetric) -> contiguous read of row n
      bf[nt] = *reinterpret_cast<const short8*>(sWb + n * 256 + (kb ^ ((n & 7) << 4)));
    }
#pragma unroll
    for (int mt = 0; mt < 4; ++mt)
#pragma unroll
      for (int nt = 0; nt < 8; ++nt)
        acc[mt][nt] = __builtin_amdgcn_mfma_f32_16x16x32_bf16(af[mt], bf[nt], acc[mt][nt], 0, 0, 0);
  }

  // ---- epilogue: K_p = sum_col E[p,col] * V[p,col]; reduce over 16 col-lanes ----
#pragma unroll
  for (int mt = 0; mt < 4; ++mt) {
    int prow_base = wave * 64 + mt * 16 + ((lane >> 4) << 2);
#pragma unroll
    for (int r = 0; r < 4; ++r) {
      int p = prow_base + r;
      float s = 0.f;
#pragma unroll
      for (int nt = 0; nt < 8; ++nt) {
        int col = nt * 16 + (lane & 15);
        unsigned short vb =
            *reinterpret_cast<const unsigned short*>(sVb + p * 256 + ((2 * col) ^ ((p & 7) << 4)));
        s += acc[mt][nt][r] * b2f(vb);
      }
      s += __shfl_xor(s, 1);
      s += __shfl_xor(s, 2);
      s += __shfl_xor(s, 4);
      s += __shfl_xor(s, 8);
      if ((lane & 15) == 0) {
        int gi = i0 + (p >> 4);
        int gj = j0 + (p & 15);
        out[gi * N2 + gj] = s * inv1[gi] * inv2[gj];
      }
    }
  }
}

// ---------------------------------------------------------------------------
extern "C" void kernel_launch(void* const* d_in, const int* in_sizes, int n_in,
                              void* d_out, int out_size, void* d_ws, size_t ws_size,
                              hipStream_t stream) {
  const int* X1 = (const int*)d_in[0];
  const int* X2 = (const int*)d_in[1];
  const float* a = (const float*)d_in[2];
  const float* A = (const float*)d_in[3];
  const float* w_vec = (const float*)d_in[4];
  float* out = (float*)d_out;

  char* ws = (char*)d_ws;
  float* S = (float*)(ws + 0);                       // 3600 B
  float* wf = (float*)(ws + 4096);                   // 64 KB
  unsigned short* wb = (unsigned short*)(ws + 4096 + 65536);  // 32 KB
  float* inv1 = (float*)(ws + 4096 + 65536 + 32768); // 3 KB
  float* inv2 = inv1 + N1;                           // 3 KB

  prep_kernel<<<1, 256, 0, stream>>>(A, w_vec, S, wf, wb);
  norm_kernel<<<N1, 128, 0, stream>>>(X1, S, wf, inv1, a, 1);
  norm_kernel<<<N2, 128, 0, stream>>>(X2, S, wf, inv2, a, 0);
  main_kernel<<<dim3(N2 / 16, N1 / 16), 256, 0, stream>>>(X1, X2, S, wb, inv1, inv2, out);
}

// Round 2
// 83.921 us; speedup vs baseline: 1.5667x; 1.5667x over previous
//
#include <hip/hip_runtime.h>
#include <hip/hip_bf16.h>

typedef __attribute__((ext_vector_type(8))) short short8;
typedef __attribute__((ext_vector_type(4))) float f32x4;

#define N1 768
#define N2 768
#define LL 128
#define NS 30

// float -> bf16 bits, round-to-nearest-even
__device__ __forceinline__ unsigned short f2b(float f) {
  unsigned int u = __float_as_uint(f);
  unsigned int r = (u + 0x7fffu + ((u >> 16) & 1u)) >> 16;
  return (unsigned short)r;
}

__device__ __forceinline__ float b2f(unsigned short b) {
  return __uint_as_float(((unsigned int)b) << 16);
}

// ---------------------------------------------------------------------------
// prep: blocks 1..32 compute w = sigmoid(W) (f32 + bf16).
//       block 0 computes Sdiag[s] = ||A[s]||^2 and the split-precision bf16
//       tables T_hl=[hi|lo], T_hh=[hi|hi], T_0l=[0|lo], rows padded to 40
//       ushorts (80 B) for LDS bank spread.
// ---------------------------------------------------------------------------
__global__ void prep_kernel(const float* __restrict__ A, const float* __restrict__ w_vec,
                            float* __restrict__ wf, unsigned short* __restrict__ wb,
                            float* __restrict__ Sdiag, unsigned short* __restrict__ Tg) {
  int b = blockIdx.x, t = threadIdx.x;
  if (b == 0) {
    for (int idx = t; idx < NS * 16; idx += 256) {
      int s = idx >> 4, c = idx & 15;
      float v = A[idx];
      unsigned short hi = f2b(v);
      unsigned short lo = f2b(v - b2f(hi));
      unsigned short* Thl = Tg;
      unsigned short* Thh = Tg + 1200;
      unsigned short* T0l = Tg + 2400;
      Thl[s * 40 + c] = hi;      Thl[s * 40 + 16 + c] = lo;
      Thh[s * 40 + c] = hi;      Thh[s * 40 + 16 + c] = hi;
      T0l[s * 40 + c] = 0;       T0l[s * 40 + 16 + c] = lo;
      if (c < 8) {  // pad region (never read, but keep LDS stage defined)
        Thl[s * 40 + 32 + c] = 0; Thh[s * 40 + 32 + c] = 0; T0l[s * 40 + 32 + c] = 0;
      }
    }
    if (t < NS) {
      float acc = 0.f;
#pragma unroll
      for (int c = 0; c < 16; ++c) { float v = A[t * 16 + c]; acc += v * v; }
      Sdiag[t] = acc;
    }
  } else {
    int base = (b - 1) * 512;
#pragma unroll
    for (int k = 0; k < 2; ++k) {
      int idx = base + k * 256 + t;
      int l = idx >> 7, m = idx & (LL - 1);
      float sig;
      if (l == m) {
        sig = 0.5f;
      } else {
        int hi = l > m ? l : m, lo = l > m ? m : l;
        sig = 1.f / (1.f + expf(-w_vec[hi * (hi - 1) / 2 + lo]));
      }
      wf[idx] = sig;
      wb[idx] = f2b(sig);
    }
  }
}

// ---------------------------------------------------------------------------
// norm: one block per row (rows 0..767 = X1 -> inv1 with a^2, 768..1535 = X2)
// inv = scale / sqrt(d^T w d),  d_l = Sdiag[x_l]
// ---------------------------------------------------------------------------
__global__ void norm_kernel(const int* __restrict__ X1, const int* __restrict__ X2,
                            const float* __restrict__ Sdiag, const float* __restrict__ wf,
                            float* __restrict__ inv1, float* __restrict__ inv2,
                            const float* __restrict__ a_ptr) {
  __shared__ __align__(16) float d[LL];
  __shared__ float wsum[2];
  int row = blockIdx.x, t = threadIdx.x;
  const int* X = (row < N1) ? (X1 + row * LL) : (X2 + (row - N1) * LL);
  float dv = Sdiag[X[t]];
  d[t] = dv;
  __syncthreads();
  const float4* w4 = reinterpret_cast<const float4*>(wf + t * LL);
  const float4* d4 = reinterpret_cast<const float4*>(d);
  float s = 0.f;
#pragma unroll
  for (int m = 0; m < LL / 4; ++m) {
    float4 wv = w4[m];
    float4 dd = d4[m];
    s += wv.x * dd.x + wv.y * dd.y + wv.z * dd.z + wv.w * dd.w;
  }
  s *= dv;
#pragma unroll
  for (int off = 1; off < 64; off <<= 1) s += __shfl_xor(s, off);
  if ((t & 63) == 0) wsum[t >> 6] = s;
  __syncthreads();
  if (t == 0) {
    float k = wsum[0] + wsum[1];
    if (row < N1) inv1[row] = a_ptr[0] * a_ptr[0] / sqrtf(k);
    else inv2[row - N1] = 1.f / sqrtf(k);
  }
}

// ---------------------------------------------------------------------------
// main: one block = 16x16 output tile (256 pairs), 512 threads (8 waves).
//  phase 1: stage W (swizzled), T tables, X index rows (padded int[16][132])
//  phase 2: V-build via MFMA: per l, V_l = A1_l @ A2_l^T with split-precision
//           (2x mfma 16x16x32), packed b64 writes into swizzled sV
//  phase 3: E = V @ W (per wave 32 pairs: 2 m-tiles x 8 n-tiles x 4 kk),
//           epilogue K_p = sum_col E*V, shfl reduce, coalesced float4 store
// ---------------------------------------------------------------------------
__global__ __launch_bounds__(512, 1) void main_kernel(
    const int* __restrict__ X1, const int* __restrict__ X2,
    const unsigned short* __restrict__ wbg, const unsigned short* __restrict__ Tg,
    const float* __restrict__ inv1, const float* __restrict__ inv2,
    float* __restrict__ out) {
  __shared__ __align__(16) unsigned short sW[LL * LL];   // 32 KB swizzled
  __shared__ __align__(16) unsigned short sV[256 * LL];  // 64 KB swizzled
  __shared__ __align__(16) int x1I[16 * 132];            // padded index rows
  __shared__ __align__(16) int x2I[16 * 132];
  __shared__ __align__(16) unsigned short sT[3600];      // 3 tables x 30 x 40

  const int t = threadIdx.x;
  const int i0 = blockIdx.y * 16, j0 = blockIdx.x * 16;
  char* sWb = reinterpret_cast<char*>(sW);
  char* sVb = reinterpret_cast<char*>(sV);

  // ---- stage W: 2048 x 16B chunks, XOR-swizzled ----
#pragma unroll
  for (int c = 0; c < 4; ++c) {
    int ch = c * 512 + t;
    int r = ch >> 4, col8 = ch & 15;
    uint4 v = reinterpret_cast<const uint4*>(wbg)[ch];
    *reinterpret_cast<uint4*>(sWb + r * 256 + ((col8 * 16) ^ ((r & 7) << 4))) = v;
  }
  // ---- stage T tables (7200 B = 450 x 16B) ----
  if (t < 450) reinterpret_cast<uint4*>(sT)[t] = reinterpret_cast<const uint4*>(Tg)[t];
  // ---- stage X rows as padded ints (conflict-free int4 writes) ----
  if (t < 256) {
    int row = t >> 4, seg = t & 15;
    const int4* p1 = reinterpret_cast<const int4*>(X1 + (i0 + row) * LL + seg * 8);
    *reinterpret_cast<int4*>(x1I + row * 132 + seg * 8) = p1[0];
    *reinterpret_cast<int4*>(x1I + row * 132 + seg * 8 + 4) = p1[1];
    const int4* p2 = reinterpret_cast<const int4*>(X2 + (j0 + row) * LL + seg * 8);
    *reinterpret_cast<int4*>(x2I + row * 132 + seg * 8) = p2[0];
    *reinterpret_cast<int4*>(x2I + row * 132 + seg * 8 + 4) = p2[1];
  }
  __syncthreads();

  const int lane = t & 63, wave = t >> 6;
  const int m = lane & 15, kg = lane >> 4;

  // ---- V-build: wave handles l in [wave*16, wave*16+16), 4 groups of 4 ----
  {
    const unsigned short* Thl = sT;
    const unsigned short* Thh = sT + 1200;
    const unsigned short* T0l = sT + 2400;
    int l0w = wave * 16;
#pragma unroll
    for (int lb = 0; lb < 4; ++lb) {
      int l0 = l0w + lb * 4;
      unsigned long long pk[4] = {0ull, 0ull, 0ull, 0ull};
#pragma unroll
      for (int q = 0; q < 4; ++q) {
        int l = l0 + q;
        int i1 = x1I[m * 132 + l];
        int i2 = x2I[m * 132 + l];
        short8 af1 = *reinterpret_cast<const short8*>(Thl + i1 * 40 + kg * 8);
        short8 bf1 = *reinterpret_cast<const short8*>(Thh + i2 * 40 + kg * 8);
        short8 af2 = *reinterpret_cast<const short8*>(Thh + i1 * 40 + kg * 8);
        short8 bf2 = *reinterpret_cast<const short8*>(T0l + i2 * 40 + kg * 8);
        f32x4 vacc = {0.f, 0.f, 0.f, 0.f};
        // hi*hi + lo*hi, then hi*lo  (lo*lo dropped, ~2^-18 rel)
        vacc = __builtin_amdgcn_mfma_f32_16x16x32_bf16(af1, bf1, vacc, 0, 0, 0);
        vacc = __builtin_amdgcn_mfma_f32_16x16x32_bf16(af2, bf2, vacc, 0, 0, 0);
#pragma unroll
        for (int r = 0; r < 4; ++r)
          pk[r] |= (unsigned long long)f2b(vacc[r]) << (16 * q);
      }
#pragma unroll
      for (int r = 0; r < 4; ++r) {
        int p = (kg * 4 + r) * 16 + m;  // D layout: col=lane&15, row=kg*4+r
        *reinterpret_cast<unsigned long long*>(
            sVb + p * 256 + ((2 * l0) ^ ((p & 7) << 4))) = pk[r];
      }
    }
  }
  __syncthreads();

  // ---- E = V @ W: per wave pairs [wave*32, wave*32+32) ----
  f32x4 acc[2][8] = {};
#pragma unroll
  for (int kk = 0; kk < 4; ++kk) {
    int kb = kk * 64 + kg * 16;
    short8 af[2], bf[8];
#pragma unroll
    for (int mt = 0; mt < 2; ++mt) {
      int p = wave * 32 + mt * 16 + m;
      af[mt] = *reinterpret_cast<const short8*>(sVb + p * 256 + (kb ^ ((p & 7) << 4)));
    }
#pragma unroll
    for (int nt = 0; nt < 8; ++nt) {
      int n = nt * 16 + m;
      bf[nt] = *reinterpret_cast<const short8*>(sWb + n * 256 + (kb ^ ((n & 7) << 4)));
    }
#pragma unroll
    for (int mt = 0; mt < 2; ++mt)
#pragma unroll
      for (int nt = 0; nt < 8; ++nt)
        acc[mt][nt] = __builtin_amdgcn_mfma_f32_16x16x32_bf16(af[mt], bf[nt], acc[mt][nt], 0, 0, 0);
  }

  // ---- epilogue: K_p = sum_col E[p,col]*V[p,col]; fused scaling; f4 store ----
#pragma unroll
  for (int mt = 0; mt < 2; ++mt) {
    int gi = i0 + wave * 2 + mt;
    float res[4];
#pragma unroll
    for (int r = 0; r < 4; ++r) {
      int p = wave * 32 + mt * 16 + kg * 4 + r;
      float s = 0.f;
#pragma unroll
      for (int nt = 0; nt < 8; ++nt) {
        int col = nt * 16 + m;
        unsigned short vb = *reinterpret_cast<const unsigned short*>(
            sVb + p * 256 + ((2 * col) ^ ((p & 7) << 4)));
        s += acc[mt][nt][r] * b2f(vb);
      }
      s += __shfl_xor(s, 1);
      s += __shfl_xor(s, 2);
      s += __shfl_xor(s, 4);
      s += __shfl_xor(s, 8);
      res[r] = s;
    }
    if (m == 0) {
      float4 iv = *reinterpret_cast<const float4*>(inv2 + j0 + kg * 4);
      float sc = inv1[gi];
      float4 o;
      o.x = res[0] * sc * iv.x;
      o.y = res[1] * sc * iv.y;
      o.z = res[2] * sc * iv.z;
      o.w = res[3] * sc * iv.w;
      *reinterpret_cast<float4*>(out + gi * N2 + j0 + kg * 4) = o;
    }
  }
}

// ---------------------------------------------------------------------------
extern "C" void kernel_launch(void* const* d_in, const int* in_sizes, int n_in,
                              void* d_out, int out_size, void* d_ws, size_t ws_size,
                              hipStream_t stream) {
  const int* X1 = (const int*)d_in[0];
  const int* X2 = (const int*)d_in[1];
  const float* a = (const float*)d_in[2];
  const float* A = (const float*)d_in[3];
  const float* w_vec = (const float*)d_in[4];
  float* out = (float*)d_out;

  char* ws = (char*)d_ws;
  float* wf = (float*)(ws + 0);                         // 64 KB
  unsigned short* wb = (unsigned short*)(ws + 65536);   // 32 KB
  float* Sdiag = (float*)(ws + 98304);                  // 128 B
  unsigned short* Tg = (unsigned short*)(ws + 98432);   // 7200 B
  float* inv1 = (float*)(ws + 105728);                  // 3 KB
  float* inv2 = inv1 + N1;                              // 3 KB

  prep_kernel<<<33, 256, 0, stream>>>(A, w_vec, wf, wb, Sdiag, Tg);
  norm_kernel<<<N1 + N2, 128, 0, stream>>>(X1, X2, Sdiag, wf, inv1, inv2, a);
  main_kernel<<<dim3(N2 / 16, N1 / 16), 512, 0, stream>>>(X1, X2, wb, Tg, inv1, inv2, out);
}